// Round 2
// baseline (1432.906 us; speedup 1.0000x reference)
//
#include <hip/hip_runtime.h>
#include <cstdint>

// Problem constants (fixed shapes)
#define E_DIM   576
#define HEADS   18
#define NPTS    12
#define DDEPTH  5
#define HDIM    32
#define BSZ     2
#define GH      64
#define GW      80
#define NQ      (GH*GW)       // 5120
#define NTOK    (NQ*DDEPTH)   // 25600
#define MIXW    (HEADS*NPTS*3 + HEADS*NPTS)  // 648 + 216 = 864

// ---------------------------------------------------------------------------
// C[M,N] = (A [+ A2]) @ B + bias ; all fp32 row-major.
// Tile 64x64, BK=16, 256 threads, 4x4 per thread.
// Requires K % 16 == 0 (K=576) and row strides 16B-aligned (all are).
__global__ void gemm_f32(const float* __restrict__ A, const float* __restrict__ A2,
                         const float* __restrict__ B, const float* __restrict__ bias,
                         float* __restrict__ C, int M, int N, int K, int ldc) {
    __shared__ float As[16][65];   // [k][m]
    __shared__ float Bs[16][65];   // [k][n]
    const int tid = threadIdx.x;
    const int row0 = blockIdx.x * 64;
    const int n0   = blockIdx.y * 64;
    const int tx = tid & 15, ty = tid >> 4;

    const int am = tid >> 2;            // 0..63 (m within tile)
    const int ak = (tid & 3) * 4;       // 0,4,8,12 (k within tile)
    const int bk = tid >> 4;            // 0..15 (k within tile)
    const int bn = (tid & 15) * 4;      // 0..60 (n within tile)

    float acc[4][4] = {};

    for (int k0 = 0; k0 < K; k0 += 16) {
        // stage A tile (transposed into [k][m]); fuse optional A2 add
        {
            const int row = row0 + am;
            float4 v = *reinterpret_cast<const float4*>(&A[(size_t)row * K + k0 + ak]);
            if (A2 != nullptr) {
                const float4 v2 = *reinterpret_cast<const float4*>(&A2[(size_t)row * K + k0 + ak]);
                v.x += v2.x; v.y += v2.y; v.z += v2.z; v.w += v2.w;
            }
            As[ak + 0][am] = v.x;
            As[ak + 1][am] = v.y;
            As[ak + 2][am] = v.z;
            As[ak + 3][am] = v.w;
        }
        // stage B tile
        {
            const int nb = n0 + bn;
            const size_t base = (size_t)(k0 + bk) * N;
            if (nb + 3 < N) {
                const float4 v = *reinterpret_cast<const float4*>(&B[base + nb]);
                Bs[bk][bn + 0] = v.x;
                Bs[bk][bn + 1] = v.y;
                Bs[bk][bn + 2] = v.z;
                Bs[bk][bn + 3] = v.w;
            } else {
                #pragma unroll
                for (int j = 0; j < 4; ++j)
                    Bs[bk][bn + j] = (nb + j < N) ? B[base + nb + j] : 0.f;
            }
        }
        __syncthreads();
        #pragma unroll
        for (int k = 0; k < 16; ++k) {
            float a[4], bb[4];
            #pragma unroll
            for (int i = 0; i < 4; ++i) a[i] = As[k][ty * 4 + i];
            #pragma unroll
            for (int j = 0; j < 4; ++j) bb[j] = Bs[k][tx * 4 + j];
            #pragma unroll
            for (int i = 0; i < 4; ++i)
                #pragma unroll
                for (int j = 0; j < 4; ++j)
                    acc[i][j] += a[i] * bb[j];
        }
        __syncthreads();
    }

    #pragma unroll
    for (int i = 0; i < 4; ++i) {
        const int row = row0 + ty * 4 + i;
        if (row >= M) continue;
        #pragma unroll
        for (int j = 0; j < 4; ++j) {
            const int col = n0 + tx * 4 + j;
            if (col >= N) continue;
            C[(size_t)row * ldc + col] = acc[i][j] + bias[col];
        }
    }
}

// ---------------------------------------------------------------------------
// Deformable 3D trilinear attention.
// One 32-lane half-wave per (b, q, head); lane = channel within head.
// vbuf: (BSZ*NTOK, E) fp32 (token-major depth-first, e = head*32 + c)
// mix:  (BSZ*NQ, 864) fp32 — [0:648) offsets (head,p,xyz), [648:864) attn logits
// aout: (BSZ*NQ, E) fp32
__global__ void deform_kernel(const float* __restrict__ vbuf,
                              const float* __restrict__ mix,
                              float* __restrict__ aout) {
    const int g = blockIdx.x * 8 + (threadIdx.x >> 5);
    const int lane = threadIdx.x & 31;
    const int head = g % HEADS;
    const int bq = g / HEADS;        // b*NQ + q
    const int q = bq % NQ;
    const int b = bq / NQ;
    const int qx = q % GW;
    const int qy = q / GW;

    const float* mrow = mix + (size_t)bq * MIXW;

    // softmax over the 12 attention logits (redundant across lanes — broadcast loads)
    float lg[NPTS];
    float mx = -1e30f;
    #pragma unroll
    for (int p = 0; p < NPTS; ++p) {
        lg[p] = mrow[648 + head * NPTS + p];
        mx = fmaxf(mx, lg[p]);
    }
    float s = 0.f;
    #pragma unroll
    for (int p = 0; p < NPTS; ++p) { lg[p] = __expf(lg[p] - mx); s += lg[p]; }
    const float inv = 1.f / s;

    const float* vb = vbuf + ((size_t)b * NTOK) * E_DIM + head * HDIM + lane;

    float out = 0.f;
    for (int p = 0; p < NPTS; ++p) {
        const int ob = (head * NPTS + p) * 3;
        const float ox = mrow[ob + 0];
        const float oy = mrow[ob + 1];
        const float oz = mrow[ob + 2];
        // ref at pixel centers: x = loc_x*W - 0.5 == qx + ox ; z = oz*D/NF - 0.5
        const float x = (float)qx + ox;
        const float y = (float)qy + oy;
        const float z = oz * (5.0f / 3.0f) - 0.5f;
        const float x0f = floorf(x), y0f = floorf(y), z0f = floorf(z);
        const int x0 = (int)x0f, y0 = (int)y0f, z0 = (int)z0f;
        const float fx = x - x0f, fy = y - y0f, fz = z - z0f;
        const float ap = lg[p] * inv;

        #pragma unroll
        for (int dz = 0; dz < 2; ++dz) {
            const int zi = z0 + dz;
            if (zi < 0 || zi >= DDEPTH) continue;
            const float wz = dz ? fz : 1.f - fz;
            #pragma unroll
            for (int dy = 0; dy < 2; ++dy) {
                const int yi = y0 + dy;
                if (yi < 0 || yi >= GH) continue;
                const float wy = dy ? fy : 1.f - fy;
                #pragma unroll
                for (int dx = 0; dx < 2; ++dx) {
                    const int xi = x0 + dx;
                    if (xi < 0 || xi >= GW) continue;
                    const float wx = dx ? fx : 1.f - fx;
                    const float wgt = ap * wz * wy * wx;
                    const size_t tok = ((size_t)zi * GH + yi) * GW + xi;
                    out += wgt * vb[tok * E_DIM];
                }
            }
        }
    }
    aout[(size_t)bq * E_DIM + head * HDIM + lane] = out;
}

// ---------------------------------------------------------------------------
extern "C" void kernel_launch(void* const* d_in, const int* in_sizes, int n_in,
                              void* d_out, int out_size, void* d_ws, size_t ws_size,
                              hipStream_t stream) {
    const float* query     = (const float*)d_in[0];
    const float* value     = (const float*)d_in[1];
    const float* query_pos = (const float*)d_in[2];
    const float* W_off     = (const float*)d_in[3];
    const float* b_off     = (const float*)d_in[4];
    const float* W_attn    = (const float*)d_in[5];
    const float* b_attn    = (const float*)d_in[6];
    const float* W_v       = (const float*)d_in[7];
    const float* b_v       = (const float*)d_in[8];
    const float* W_out     = (const float*)d_in[9];
    const float* b_out     = (const float*)d_in[10];
    float* out = (float*)d_out;

    char* ws = (char*)d_ws;
    // layout (all 16B-aligned):
    float* vbuf = (float*)(ws);                               // 51200*576*4 = 117,964,800 B
    float* mixb = (float*)(ws + 117964800);                   // 10240*864*4 =  35,389,440 B
    float* aout = (float*)(ws + 117964800 + 35389440);        // 10240*576*4 =  23,592,960 B

    // offs = (query+query_pos) @ W_off + b_off : (10240 x 648) -> mix[:, 0:648]
    gemm_f32<<<dim3(10240 / 64, (648 + 63) / 64), 256, 0, stream>>>(
        query, query_pos, W_off, b_off, mixb, BSZ * NQ, 648, E_DIM, MIXW);

    // attn logits = (query+query_pos) @ W_attn + b_attn : (10240 x 216) -> mix[:, 648:864]
    gemm_f32<<<dim3(10240 / 64, (216 + 63) / 64), 256, 0, stream>>>(
        query, query_pos, W_attn, b_attn, mixb + 648, BSZ * NQ, 216, E_DIM, MIXW);

    // v = value @ W_v + b_v : (51200 x 576)
    gemm_f32<<<dim3(51200 / 64, 576 / 64), 256, 0, stream>>>(
        value, nullptr, W_v, b_v, vbuf, BSZ * NTOK, E_DIM, E_DIM, E_DIM);

    // deformable gather + softmax-weighted sum
    const int ngroups = BSZ * NQ * HEADS;   // 184,320
    deform_kernel<<<ngroups / 8, 256, 0, stream>>>(vbuf, mixb, aout);

    // out = attn_out @ W_out + b_out : (10240 x 576)
    gemm_f32<<<dim3(10240 / 64, 576 / 64), 256, 0, stream>>>(
        aout, nullptr, W_out, b_out, out, BSZ * NQ, E_DIM, E_DIM, E_DIM);
}

// Round 3
// 447.956 us; speedup vs baseline: 3.1988x; 3.1988x over previous
//
#include <hip/hip_runtime.h>
#include <cstdint>

// Problem constants (fixed shapes)
#define E_DIM   576
#define HEADS   18
#define NPTS    12
#define DDEPTH  5
#define HDIM    32
#define BSZ     2
#define GH      64
#define GW      80
#define NQ      (GH*GW)       // 5120
#define NTOK    (NQ*DDEPTH)   // 25600
#define MIXW    864           // 648 offsets + 216 attn logits

typedef __attribute__((ext_vector_type(8))) short short8;
typedef __attribute__((ext_vector_type(4))) float f32x4;

__device__ __forceinline__ float b2f(uint32_t u16) {
    union { uint32_t u; float f; } v; v.u = u16 << 16; return v.f;
}
__device__ __forceinline__ ushort f2b(float f) {
    union { float f; uint32_t u; } v; v.f = f;
    return (ushort)((v.u + 0x7fffu + ((v.u >> 16) & 1u)) >> 16);
}

// ---------------------------------------------------------------------------
// casts
__global__ void cast_kernel(const float* __restrict__ in, ushort* __restrict__ out, int n4) {
    int i = blockIdx.x * blockDim.x + threadIdx.x;
    if (i >= n4) return;
    const float4 v = reinterpret_cast<const float4*>(in)[i];
    ushort4 o; o.x = f2b(v.x); o.y = f2b(v.y); o.z = f2b(v.z); o.w = f2b(v.w);
    reinterpret_cast<ushort4*>(out)[i] = o;
}

__global__ void cast_add_kernel(const float* __restrict__ a, const float* __restrict__ b,
                                ushort* __restrict__ out, int n4) {
    int i = blockIdx.x * blockDim.x + threadIdx.x;
    if (i >= n4) return;
    const float4 va = reinterpret_cast<const float4*>(a)[i];
    const float4 vb = reinterpret_cast<const float4*>(b)[i];
    ushort4 o;
    o.x = f2b(va.x + vb.x); o.y = f2b(va.y + vb.y);
    o.z = f2b(va.z + vb.z); o.w = f2b(va.w + vb.w);
    reinterpret_cast<ushort4*>(out)[i] = o;
}

// Wt[n*K + k] = W[k*N + n], bf16
__global__ void transpose_cast(const float* __restrict__ W, ushort* __restrict__ Wt,
                               int K, int N) {
    int idx = blockIdx.x * blockDim.x + threadIdx.x;
    if (idx >= N * K) return;
    int n = idx / K, k = idx - n * K;
    Wt[idx] = f2b(W[(size_t)k * N + n]);
}

// combined mix weight (rows 0..647 from W_off^T, 648..863 from W_attn^T) + bias concat
__global__ void build_wt_mix(const float* __restrict__ W_off, const float* __restrict__ W_attn,
                             const float* __restrict__ b_off, const float* __restrict__ b_attn,
                             ushort* __restrict__ Wt, float* __restrict__ bias) {
    int idx = blockIdx.x * blockDim.x + threadIdx.x;
    if (idx >= MIXW * E_DIM) return;
    int n = idx / E_DIM, k = idx - n * E_DIM;
    float v = (n < 648) ? W_off[(size_t)k * 648 + n] : W_attn[(size_t)k * 216 + (n - 648)];
    Wt[idx] = f2b(v);
    if (idx < MIXW) bias[idx] = (idx < 648) ? b_off[idx] : b_attn[idx - 648];
}

// ---------------------------------------------------------------------------
// MFMA GEMM: C[M,N] = A[M,K] @ Bt[N,K]^T + bias[N]
// A, Bt bf16; bias fp32; OutT in {float(4B), ushort(bf16)}
// Tile 128x96, BK=32, 256 threads = 4 waves; wave w covers rows [w*32, w*32+32)
// of the tile x all 96 cols. Requires M%128==0, N%96==0, K%32==0 (all hold).
#define TM 128
#define TN 96
#define BK 32

__device__ __forceinline__ void async_cp16(const ushort* gsrc, ushort* ldst) {
    __builtin_amdgcn_global_load_lds(
        (const __attribute__((address_space(1))) void*)gsrc,
        (__attribute__((address_space(3))) void*)ldst, 16, 0, 0);
}

template <typename OutT>
__global__ void gemm_mfma(const ushort* __restrict__ A, const ushort* __restrict__ Bt,
                          const float* __restrict__ bias, OutT* __restrict__ C,
                          int M, int N, int K, int ldc) {
    __shared__ __align__(16) ushort Asb[TM * BK];   // [m][k]
    __shared__ __align__(16) ushort Bsb[TN * BK];   // [n][k]
    const int tid  = threadIdx.x;
    const int wave = tid >> 6;
    const int lane = tid & 63;
    const int m16  = lane & 15;
    const int quad = lane >> 4;
    const int row0 = blockIdx.x * TM;
    const int n0   = blockIdx.y * TN;

    const f32x4 zero = {0.f, 0.f, 0.f, 0.f};
    f32x4 acc[2][6];
    #pragma unroll
    for (int rt = 0; rt < 2; ++rt)
        #pragma unroll
        for (int ct = 0; ct < 6; ++ct) acc[rt][ct] = zero;

    // per-lane source offsets for staging (16 rows x 32 cols per issue)
    const int srow = lane >> 2;          // 0..15
    const int scol = (lane & 3) * 8;     // 0,8,16,24

    for (int k0 = 0; k0 < K; k0 += BK) {
        // stage A: 8 chunks of 16 rows, round-robin over waves
        #pragma unroll
        for (int c = 0; c < 2; ++c) {
            const int ch = wave + c * 4;
            async_cp16(A + (size_t)(row0 + ch * 16 + srow) * K + k0 + scol,
                       Asb + ch * 512 + lane * 8);
        }
        // stage Bt: 6 chunks of 16 rows
        {
            const int ch = wave;   // 0..3
            if (ch < 6)
                async_cp16(Bt + (size_t)(n0 + ch * 16 + srow) * K + k0 + scol,
                           Bsb + ch * 512 + lane * 8);
            const int ch2 = wave + 4;
            if (ch2 < 6)
                async_cp16(Bt + (size_t)(n0 + ch2 * 16 + srow) * K + k0 + scol,
                           Bsb + ch2 * 512 + lane * 8);
        }
        __syncthreads();   // drains vmcnt (global_load_lds) before LDS reads

        short8 afrag[2], bfrag[6];
        #pragma unroll
        for (int rt = 0; rt < 2; ++rt)
            afrag[rt] = *reinterpret_cast<const short8*>(
                Asb + (wave * 32 + rt * 16 + m16) * BK + quad * 8);
        #pragma unroll
        for (int ct = 0; ct < 6; ++ct)
            bfrag[ct] = *reinterpret_cast<const short8*>(
                Bsb + (ct * 16 + m16) * BK + quad * 8);

        #pragma unroll
        for (int rt = 0; rt < 2; ++rt)
            #pragma unroll
            for (int ct = 0; ct < 6; ++ct)
                acc[rt][ct] = __builtin_amdgcn_mfma_f32_16x16x32_bf16(
                    afrag[rt], bfrag[ct], acc[rt][ct], 0, 0, 0);

        __syncthreads();   // protect LDS before next-iter overwrite
    }

    // epilogue: C/D layout col=lane&15, row=quad*4+reg
    #pragma unroll
    for (int ct = 0; ct < 6; ++ct) {
        const int col = n0 + ct * 16 + m16;
        const float bcol = bias[col];
        #pragma unroll
        for (int rt = 0; rt < 2; ++rt) {
            #pragma unroll
            for (int r = 0; r < 4; ++r) {
                const int row = row0 + wave * 32 + rt * 16 + quad * 4 + r;
                const float val = acc[rt][ct][r] + bcol;
                if constexpr (__is_same(OutT, float)) {
                    C[(size_t)row * ldc + col] = val;
                } else {
                    C[(size_t)row * ldc + col] = f2b(val);
                }
            }
        }
    }
}

// ---------------------------------------------------------------------------
// Deformable 3D trilinear attention. 16 lanes per (b,q,head) group; each lane
// handles 2 channels via dword loads from bf16 vbuf.
// vbuf: (BSZ*NTOK, E) bf16 ; mix: (BSZ*NQ, 864) fp32 ; aout: (BSZ*NQ, E) bf16
__global__ void deform_kernel(const ushort* __restrict__ vbuf,
                              const float* __restrict__ mix,
                              ushort* __restrict__ aout) {
    const int g = blockIdx.x * 16 + (threadIdx.x >> 4);
    const int lane = threadIdx.x & 15;   // channel pair
    const int head = g % HEADS;
    const int bq = g / HEADS;
    const int q = bq % NQ;
    const int b = bq / NQ;
    const int qx = q % GW;
    const int qy = q / GW;

    const float* mrow = mix + (size_t)bq * MIXW;

    // softmax over 12 logits (broadcast across lanes)
    float lg[NPTS];
    float mx = -1e30f;
    #pragma unroll
    for (int p = 0; p < NPTS; ++p) {
        lg[p] = mrow[648 + head * NPTS + p];
        mx = fmaxf(mx, lg[p]);
    }
    float s = 0.f;
    #pragma unroll
    for (int p = 0; p < NPTS; ++p) { lg[p] = __expf(lg[p] - mx); s += lg[p]; }
    const float inv = 1.f / s;

    const uint32_t* vb = reinterpret_cast<const uint32_t*>(
        vbuf + (size_t)b * NTOK * E_DIM + head * HDIM) + lane;

    float out0 = 0.f, out1 = 0.f;
    for (int p = 0; p < NPTS; ++p) {
        const int ob = (head * NPTS + p) * 3;
        const float ox = mrow[ob + 0];
        const float oy = mrow[ob + 1];
        const float oz = mrow[ob + 2];
        // ref at pixel centers: x = loc_x*W - 0.5 == qx + ox ; z = oz*D/NF - 0.5
        const float x = (float)qx + ox;
        const float y = (float)qy + oy;
        const float z = oz * (5.0f / 3.0f) - 0.5f;
        const float x0f = floorf(x), y0f = floorf(y), z0f = floorf(z);
        const int x0 = (int)x0f, y0 = (int)y0f, z0 = (int)z0f;
        const float fx = x - x0f, fy = y - y0f, fz = z - z0f;
        const float ap = lg[p] * inv;

        #pragma unroll
        for (int dz = 0; dz < 2; ++dz) {
            const int zi = z0 + dz;
            if (zi < 0 || zi >= DDEPTH) continue;
            const float wz = dz ? fz : 1.f - fz;
            #pragma unroll
            for (int dy = 0; dy < 2; ++dy) {
                const int yi = y0 + dy;
                if (yi < 0 || yi >= GH) continue;
                const float wy = dy ? fy : 1.f - fy;
                #pragma unroll
                for (int dx = 0; dx < 2; ++dx) {
                    const int xi = x0 + dx;
                    if (xi < 0 || xi >= GW) continue;
                    const float wgt = ap * wz * wy * (dx ? fx : 1.f - fx);
                    const size_t tok = ((size_t)zi * GH + yi) * GW + xi;
                    const uint32_t pair = vb[tok * (E_DIM / 2)];
                    out0 += wgt * b2f(pair & 0xffffu);
                    out1 += wgt * b2f(pair >> 16);
                }
            }
        }
    }
    const uint32_t packed = (uint32_t)f2b(out0) | ((uint32_t)f2b(out1) << 16);
    reinterpret_cast<uint32_t*>(aout + (size_t)bq * E_DIM + head * HDIM)[lane] = packed;
}

// ---------------------------------------------------------------------------
extern "C" void kernel_launch(void* const* d_in, const int* in_sizes, int n_in,
                              void* d_out, int out_size, void* d_ws, size_t ws_size,
                              hipStream_t stream) {
    const float* query     = (const float*)d_in[0];
    const float* value     = (const float*)d_in[1];
    const float* query_pos = (const float*)d_in[2];
    const float* W_off     = (const float*)d_in[3];
    const float* b_off     = (const float*)d_in[4];
    const float* W_attn    = (const float*)d_in[5];
    const float* b_attn    = (const float*)d_in[6];
    const float* W_v       = (const float*)d_in[7];
    const float* b_v       = (const float*)d_in[8];
    const float* W_out     = (const float*)d_in[9];
    const float* b_out     = (const float*)d_in[10];
    float* out = (float*)d_out;

    char* ws = (char*)d_ws;
    // layout (all 16B-aligned); aout aliases val_bf16 (dead after value GEMM)
    ushort* vbuf     = (ushort*)(ws);                  // 51200*576*2 = 58,982,400
    ushort* val_bf16 = (ushort*)(ws + 58982400);       // 58,982,400
    ushort* aout     = val_bf16;                       // alias (after value GEMM)
    ushort* q_bf16   = (ushort*)(ws + 117964800);      // 10240*576*2 = 11,796,480
    float*  mixb     = (float*) (ws + 129761280);      // 10240*864*4 = 35,389,440
    ushort* wt_v     = (ushort*)(ws + 165150720);      // 576*576*2 = 663,552
    ushort* wt_out   = (ushort*)(ws + 165814272);      // 663,552
    ushort* wt_mix   = (ushort*)(ws + 166477824);      // 864*576*2 = 995,328
    float*  bias_mix = (float*) (ws + 167473152);      // 864*4

    // prep: casts + weight transposes
    cast_kernel<<<(51200 * 576 / 4 + 255) / 256, 256, 0, stream>>>(value, val_bf16, 51200 * 576 / 4);
    cast_add_kernel<<<(10240 * 576 / 4 + 255) / 256, 256, 0, stream>>>(query, query_pos, q_bf16, 10240 * 576 / 4);
    transpose_cast<<<(576 * 576 + 255) / 256, 256, 0, stream>>>(W_v, wt_v, E_DIM, E_DIM);
    transpose_cast<<<(576 * 576 + 255) / 256, 256, 0, stream>>>(W_out, wt_out, E_DIM, E_DIM);
    build_wt_mix<<<(864 * 576 + 255) / 256, 256, 0, stream>>>(W_off, W_attn, b_off, b_attn, wt_mix, bias_mix);

    // mix = q @ [W_off|W_attn] + bias : (10240 x 864), fp32 out
    gemm_mfma<float><<<dim3(10240 / TM, MIXW / TN), 256, 0, stream>>>(
        q_bf16, wt_mix, bias_mix, mixb, BSZ * NQ, MIXW, E_DIM, MIXW);

    // v = value @ W_v + b_v : (51200 x 576), bf16 out
    gemm_mfma<ushort><<<dim3(51200 / TM, E_DIM / TN), 256, 0, stream>>>(
        val_bf16, wt_v, b_v, vbuf, BSZ * NTOK, E_DIM, E_DIM, E_DIM);

    // deformable gather + softmax-weighted sum -> aout (bf16)
    deform_kernel<<<BSZ * NQ * HEADS / 16, 256, 0, stream>>>(vbuf, mixb, aout);

    // out = aout @ W_out + b_out : (10240 x 576), fp32 to d_out
    gemm_mfma<float><<<dim3(10240 / TM, E_DIM / TN), 256, 0, stream>>>(
        aout, wt_out, b_out, out, BSZ * NQ, E_DIM, E_DIM, E_DIM);
}